// Round 7
// baseline (408.051 us; speedup 1.0000x reference)
//
#include <hip/hip_runtime.h>
#include <hip/hip_bf16.h>
#include <cstddef>
#include <cstdint>

#define B_   2
#define S_   2048
#define H_   2048
#define NH_  32
#define NKV_ 8
#define HD_  64

typedef __attribute__((ext_vector_type(8))) short short8;
typedef __attribute__((ext_vector_type(4))) float v4f;
typedef __attribute__((ext_vector_type(16))) float v16f;

#define MAXC 48.0f
#define QSCALE 0.18033688011112042f   /* 0.125 * log2(e) */

__device__ __forceinline__ unsigned short f2b(float f) {
    unsigned int u = __float_as_uint(f);
    u += 0x7FFFu + ((u >> 16) & 1u);
    return (unsigned short)(u >> 16);
}
__device__ __forceinline__ unsigned int pkbf(float a, float b) {
    __hip_bfloat162 h = __float22bfloat162_rn(float2{a, b});
    return *(unsigned int*)&h;
}
__device__ __forceinline__ v4f mfma16(short8 a, short8 b, v4f c) {
    return __builtin_amdgcn_mfma_f32_16x16x32_bf16(a, b, c, 0, 0, 0);
}
__device__ __forceinline__ v16f mfma32(short8 a, short8 b, v16f c) {
    return __builtin_amdgcn_mfma_f32_32x32x16_bf16(a, b, c, 0, 0, 0);
}
__device__ __forceinline__ void gll16(void* lds, const void* g) {
    __builtin_amdgcn_global_load_lds(
        (const __attribute__((address_space(1))) unsigned int*)g,
        (__attribute__((address_space(3))) unsigned int*)lds, 16, 0, 0);
}

// ---------------------------------------------------------------------------
// fp32 -> bf16 conversion for x, Wq, Wk, Wv, Wo
// ---------------------------------------------------------------------------
__global__ __launch_bounds__(256) void convert_all(
    const float* __restrict__ x, const float* __restrict__ wq,
    const float* __restrict__ wk, const float* __restrict__ wv,
    const float* __restrict__ wo,
    unsigned short* __restrict__ xb, unsigned short* __restrict__ wqb,
    unsigned short* __restrict__ wkb, unsigned short* __restrict__ wvb,
    unsigned short* __restrict__ wob)
{
    size_t i = ((size_t)blockIdx.x * 256 + threadIdx.x) * 4;
    const float* src; unsigned short* dst; size_t off;
    if (i < 8388608)       { src = x;  dst = xb;  off = i; }
    else if (i < 12582912) { src = wq; dst = wqb; off = i - 8388608; }
    else if (i < 13631488) { src = wk; dst = wkb; off = i - 12582912; }
    else if (i < 14680064) { src = wv; dst = wvb; off = i - 13631488; }
    else                   { src = wo; dst = wob; off = i - 14680064; }
    float4 v = *(const float4*)(src + off);
    ushort4 o;
    o.x = f2b(v.x); o.y = f2b(v.y); o.z = f2b(v.z); o.w = f2b(v.w);
    *(ushort4*)(dst + off) = o;
}

// ---------------------------------------------------------------------------
// Fused QKV GEMM + RoPE epilogue. 128x128 tile, BK=64, XOR-swizzled LDS.
// blockIdx.x: 0-15 Q (RoPE+QSCALE), 16-19 K (RoPE), 20-23 V transposed
// (A=Wv, B=x -> Vt[d][m] coalesced).
// ---------------------------------------------------------------------------
__global__ __launch_bounds__(256) void qkv_gemm(
    const unsigned short* __restrict__ xb,
    const unsigned short* __restrict__ wqb, const unsigned short* __restrict__ wkb,
    const unsigned short* __restrict__ wvb,
    const float* __restrict__ bq, const float* __restrict__ bk,
    const float* __restrict__ bv,
    const float* __restrict__ fc, const float* __restrict__ fs,
    unsigned short* __restrict__ Qb, unsigned short* __restrict__ Kb,
    unsigned short* __restrict__ Vt)
{
    __shared__ unsigned short As[128 * 64];
    __shared__ unsigned short Bs[128 * 64];
    const int tid = threadIdx.x;
    const int lane = tid & 63, w = tid >> 6;
    const int tx = lane & 15, quad = lane >> 4;
    const int bx = blockIdx.x, by = blockIdx.y;

    const unsigned short *Ap, *Bp;
    int mode, aBase, bBase;
    if (bx < 16)      { mode = 0; Ap = xb;  Bp = wqb; aBase = by * 128; bBase = bx * 128; }
    else if (bx < 20) { mode = 1; Ap = xb;  Bp = wkb; aBase = by * 128; bBase = (bx - 16) * 128; }
    else              { mode = 2; Ap = wvb; Bp = xb;  aBase = (bx - 20) * 128; bBase = by * 128; }

    const int wm = (w >> 1) * 64, wn = (w & 1) * 64;
    v4f acc[4][4];
#pragma unroll
    for (int i = 0; i < 4; ++i)
#pragma unroll
        for (int j = 0; j < 4; ++j) acc[i][j] = (v4f)0.f;

    const int r8 = lane >> 3, gc = (lane & 7) ^ r8;
    const unsigned short* ga = &Ap[(size_t)(aBase + w * 32 + r8) * 2048 + gc * 8];
    const unsigned short* gb = &Bp[(size_t)(bBase + w * 32 + r8) * 2048 + gc * 8];

    const int t7 = tx & 7;
    int sl[2];
#pragma unroll
    for (int kk = 0; kk < 2; ++kk) sl[kk] = ((kk * 4 + quad) ^ t7) * 8;

    for (int k0 = 0; k0 < 2048; k0 += 64) {
        __syncthreads();
#pragma unroll
        for (int i = 0; i < 4; ++i) {
            gll16(&As[(w * 32 + i * 8) * 64], ga + (size_t)(i * 8) * 2048 + k0);
            gll16(&Bs[(w * 32 + i * 8) * 64], gb + (size_t)(i * 8) * 2048 + k0);
        }
        __syncthreads();
#pragma unroll
        for (int kk = 0; kk < 2; ++kk) {
            short8 af[4], bf[4];
#pragma unroll
            for (int mt = 0; mt < 4; ++mt)
                af[mt] = *(const short8*)&As[(wm + mt * 16 + tx) * 64 + sl[kk]];
#pragma unroll
            for (int nt = 0; nt < 4; ++nt)
                bf[nt] = *(const short8*)&Bs[(wn + nt * 16 + tx) * 64 + sl[kk]];
#pragma unroll
            for (int mt = 0; mt < 4; ++mt)
#pragma unroll
                for (int nt = 0; nt < 4; ++nt)
                    acc[mt][nt] = mfma16(af[mt], bf[nt], acc[mt][nt]);
        }
    }

    if (mode <= 1) {
        unsigned short* Cout = mode ? Kb : Qb;
        const float* bias    = mode ? bk : bq;
        const int ldN        = mode ? 512 : 2048;
        const float scq      = mode ? 1.0f : QSCALE;
        float bx0 = bias[bBase + wn +  0 + tx];
        float bx1 = bias[bBase + wn + 16 + tx];
        float bx2 = bias[bBase + wn + 32 + tx];
        float bx3 = bias[bBase + wn + 48 + tx];
#pragma unroll
        for (int mt = 0; mt < 4; ++mt)
#pragma unroll
            for (int rg = 0; rg < 4; ++rg) {
                int m = aBase + wm + mt * 16 + quad * 4 + rg;
                int s = m & (S_ - 1);
                float c0 = fc[s * 32 + tx],      c1 = fc[s * 32 + 16 + tx];
                float s0 = fs[s * 32 + tx],      s1 = fs[s * 32 + 16 + tx];
                float q0 = acc[mt][0][rg] + bx0, q1 = acc[mt][1][rg] + bx1;
                float q2 = acc[mt][2][rg] + bx2, q3 = acc[mt][3][rg] + bx3;
                size_t base = (size_t)m * ldN + bBase + wn + tx;
                Cout[base]      = f2b((q0 * c0 - q2 * s0) * scq);
                Cout[base + 16] = f2b((q1 * c1 - q3 * s1) * scq);
                Cout[base + 32] = f2b((q2 * c0 + q0 * s0) * scq);
                Cout[base + 48] = f2b((q3 * c1 + q1 * s1) * scq);
            }
    } else {
#pragma unroll
        for (int mt = 0; mt < 4; ++mt)
#pragma unroll
            for (int rg = 0; rg < 4; ++rg) {
                int d = aBase + wm + mt * 16 + quad * 4 + rg;
                float bvv = bv[d];
                size_t base = (size_t)d * 4096 + bBase + wn + tx;
#pragma unroll
                for (int nt = 0; nt < 4; ++nt)
                    Vt[base + nt * 16] = f2b(acc[mt][nt][rg] + bvv);
            }
    }
}

// ---------------------------------------------------------------------------
// Output GEMM, BK=64, direct fp32 store.
// ---------------------------------------------------------------------------
__global__ __launch_bounds__(256) void out_gemm(
    const unsigned short* __restrict__ Ab, const unsigned short* __restrict__ Bw,
    float* __restrict__ C)
{
    __shared__ unsigned short As[128 * 64];
    __shared__ unsigned short Bs[128 * 64];
    const int tid = threadIdx.x;
    const int lane = tid & 63, w = tid >> 6;
    const int tx = lane & 15, quad = lane >> 4;
    const int bm = blockIdx.y * 128, bn = blockIdx.x * 128;
    const int wm = (w >> 1) * 64, wn = (w & 1) * 64;

    v4f acc[4][4];
#pragma unroll
    for (int i = 0; i < 4; ++i)
#pragma unroll
        for (int j = 0; j < 4; ++j) acc[i][j] = (v4f)0.f;

    const int r8 = lane >> 3, gc = (lane & 7) ^ r8;
    const unsigned short* ga = &Ab[(size_t)(bm + w * 32 + r8) * 2048 + gc * 8];
    const unsigned short* gb = &Bw[(size_t)(bn + w * 32 + r8) * 2048 + gc * 8];
    const int t7 = tx & 7;
    int sl[2];
#pragma unroll
    for (int kk = 0; kk < 2; ++kk) sl[kk] = ((kk * 4 + quad) ^ t7) * 8;

    for (int k0 = 0; k0 < 2048; k0 += 64) {
        __syncthreads();
#pragma unroll
        for (int i = 0; i < 4; ++i) {
            gll16(&As[(w * 32 + i * 8) * 64], ga + (size_t)(i * 8) * 2048 + k0);
            gll16(&Bs[(w * 32 + i * 8) * 64], gb + (size_t)(i * 8) * 2048 + k0);
        }
        __syncthreads();
#pragma unroll
        for (int kk = 0; kk < 2; ++kk) {
            short8 af[4], bf[4];
#pragma unroll
            for (int mt = 0; mt < 4; ++mt)
                af[mt] = *(const short8*)&As[(wm + mt * 16 + tx) * 64 + sl[kk]];
#pragma unroll
            for (int nt = 0; nt < 4; ++nt)
                bf[nt] = *(const short8*)&Bs[(wn + nt * 16 + tx) * 64 + sl[kk]];
#pragma unroll
            for (int mt = 0; mt < 4; ++mt)
#pragma unroll
                for (int nt = 0; nt < 4; ++nt)
                    acc[mt][nt] = mfma16(af[mt], bf[nt], acc[mt][nt]);
        }
    }
#pragma unroll
    for (int mt = 0; mt < 4; ++mt)
#pragma unroll
        for (int nt = 0; nt < 4; ++nt)
#pragma unroll
            for (int rg = 0; rg < 4; ++rg) {
                int m = bm + wm + mt * 16 + quad * 4 + rg;
                C[(size_t)m * 2048 + bn + wn + nt * 16 + tx] = acc[mt][nt][rg];
            }
}

// ---------------------------------------------------------------------------
// MFMA flash attention v3: ZERO LDS, ZERO barriers. Each wave independent.
// For 32x32x16 the A-frag row (m=lane&31) is a contiguous 16B run in global
// for both K (row-major) and V^T (Vt[d][m]) -> frags load straight from
// global (L1/L2-cached; 8 q-tiles x 4 heads reuse each KV tile). Causal
// pairing: waves 0,1 -> tile p, waves 2,3 -> tile 31-p (balanced trip counts).
// S^T = K*Q^T with acc init -MAXC; p=exp2(st); C->B-frag via shfl half-swap.
// ---------------------------------------------------------------------------
__global__ __launch_bounds__(256) void attn_mfma(
    const unsigned short* __restrict__ Q, const unsigned short* __restrict__ K,
    const unsigned short* __restrict__ Vt, unsigned short* __restrict__ O)
{
    const int tid = threadIdx.x;
    const int lane = tid & 63, wq = tid >> 6;
    const int l32 = lane & 31, half = lane >> 5;
    const int p = blockIdx.x, h = blockIdx.y, b = blockIdx.z;
    const int kvh = h >> 2;
    const int qtw = (wq < 2) ? p : (31 - p);

    // Q B-frags: n=q row is lane-contiguous 16B in global
    const int qrow = qtw * 64 + (wq & 1) * 32 + l32;
    const unsigned short* Qr = &Q[(((size_t)b * S_ + qrow) * NH_ + h) * HD_];
    short8 qf[4];
#pragma unroll
    for (int s = 0; s < 4; ++s)
        qf[s] = *(const short8*)(Qr + s * 16 + half * 8);

    // per-lane frag row pointers (include half*8 column offset)
    const unsigned short* Kr  = &K[(((size_t)b * S_ + l32) * NKV_ + kvh) * HD_ + half * 8];
    const unsigned short* Vr0 = &Vt[(size_t)(kvh * 64 + l32) * 4096 + b * 2048 + half * 8];
    const unsigned short* Vr1 = Vr0 + 32 * 4096;

    float l = 0.f;
    v16f o0 = (v16f)0.f, o1 = (v16f)0.f;

    for (int kt = 0; kt <= qtw; ++kt) {
        const bool diag = (kt == qtw);
        const int tpart = diag ? (wq & 1) : 2;
        const unsigned short* Kt  = Kr + (size_t)kt * 64 * 512;
        const unsigned short* Vk0 = Vr0 + kt * 64;
        const unsigned short* Vk1 = Vr1 + kt * 64;

        for (int t = 0; t < 2; ++t) {
            if (diag && t > tpart) break;
            const unsigned short* Ka = Kt + (size_t)t * 32 * 512;
            v16f st = (v16f)(-MAXC);
            st = mfma32(*(const short8*)(Ka),      qf[0], st);
            st = mfma32(*(const short8*)(Ka + 16), qf[1], st);
            st = mfma32(*(const short8*)(Ka + 32), qf[2], st);
            st = mfma32(*(const short8*)(Ka + 48), qf[3], st);
            const bool part = diag && (t == tpart);
            float pv[16];
#pragma unroll
            for (int r = 0; r < 16; ++r) {
                int krow = (r & 3) + 8 * (r >> 2) + 4 * half;
                bool msk = part && (krow > l32);
                pv[r] = msk ? 0.f : exp2f(st[r]);
                l += pv[r];
            }
            unsigned int u[8];
#pragma unroll
            for (int g = 0; g < 4; ++g) {
                u[2 * g]     = pkbf(pv[4 * g],     pv[4 * g + 1]);
                u[2 * g + 1] = pkbf(pv[4 * g + 2], pv[4 * g + 3]);
            }
            // C-layout -> B-frag via half-swap (lane <-> lane^32)
#pragma unroll
            for (int sg = 0; sg < 2; ++sg) {
                unsigned int a0 = u[4 * sg],     a1 = u[4 * sg + 1];
                unsigned int b0 = u[4 * sg + 2], b1 = u[4 * sg + 3];
                unsigned int s0 = __shfl_xor((int)a0, 32);
                unsigned int s1 = __shfl_xor((int)a1, 32);
                unsigned int s2 = __shfl_xor((int)b0, 32);
                unsigned int s3 = __shfl_xor((int)b1, 32);
                uint4 fw;
                fw.x = half ? s2 : a0;
                fw.y = half ? s3 : a1;
                fw.z = half ? b0 : s0;
                fw.w = half ? b1 : s1;
                short8 pf = *(short8*)&fw;
                const int vo = (2 * t + sg) * 16;
                o0 = mfma32(*(const short8*)(Vk0 + vo), pf, o0);
                o1 = mfma32(*(const short8*)(Vk1 + vo), pf, o1);
            }
        }
    }

    l += __shfl_xor(l, 32);
    float inv = 1.f / l;
    unsigned short* orow = &O[((size_t)b * S_ + qrow) * (NH_ * HD_) + h * HD_];
#pragma unroll
    for (int td = 0; td < 2; ++td) {
        const v16f& oo = td ? o1 : o0;
#pragma unroll
        for (int g = 0; g < 4; ++g) {
            int d = td * 32 + g * 8 + half * 4;
            uint2 uu;
            uu.x = pkbf(oo[4 * g] * inv,     oo[4 * g + 1] * inv);
            uu.y = pkbf(oo[4 * g + 2] * inv, oo[4 * g + 3] * inv);
            *(uint2*)&orow[d] = uu;
        }
    }
}

// ---------------------------------------------------------------------------
extern "C" void kernel_launch(void* const* d_in, const int* in_sizes, int n_in,
                              void* d_out, int out_size, void* d_ws, size_t ws_size,
                              hipStream_t stream)
{
    const float* x  = (const float*)d_in[0];
    const float* fc = (const float*)d_in[1];
    const float* fs = (const float*)d_in[2];
    // d_in[3] = mask: causal, applied structurally
    const float* Wq = (const float*)d_in[4];
    const float* bq = (const float*)d_in[5];
    const float* Wk = (const float*)d_in[6];
    const float* bk = (const float*)d_in[7];
    const float* Wv = (const float*)d_in[8];
    const float* bv = (const float*)d_in[9];
    const float* Wo = (const float*)d_in[10];
    float* out = (float*)d_out;

    unsigned short* ws = (unsigned short*)d_ws;
    unsigned short* xb  = ws;                  // 8388608
    unsigned short* wqb = ws + 8388608;        // 4194304
    unsigned short* wkb = ws + 12582912;       // 1048576
    unsigned short* wvb = ws + 13631488;       // 1048576
    unsigned short* wob = ws + 14680064;       // 4194304
    unsigned short* Qb  = ws + 18874368;       // 8388608
    unsigned short* Kb  = ws + 27262976;       // 2097152
    unsigned short* Vt  = ws + 29360128;       // 2097152
    unsigned short* Ob  = ws + 31457280;       // 8388608

    dim3 blk(256);
    convert_all<<<18432, blk, 0, stream>>>(x, Wq, Wk, Wv, Wo, xb, wqb, wkb, wvb, wob);
    qkv_gemm<<<dim3(24, 32), blk, 0, stream>>>(xb, wqb, wkb, wvb, bq, bk, bv,
                                               fc, fs, Qb, Kb, Vt);
    attn_mfma<<<dim3(16, NH_, B_), blk, 0, stream>>>(Qb, Kb, Vt, Ob);
    out_gemm<<<dim3(16, 32), blk, 0, stream>>>(Ob, wob, out);
}